// Round 5
// baseline (302.466 us; speedup 1.0000x reference)
//
#include <hip/hip_runtime.h>
#include <math.h>

// ---------------------------------------------------------------------------
// out = DHT2_128( crop_center_128( DHT2_256(x) ) ), x: (512, 256, 256) fp32.
// Single fused kernel, one image per block, 512 threads (8 waves), 69.6 KB LDS
// -> 2 blocks/CU. bf16 MFMA 16x16x32. Hartley symmetry Q[v] = P[(N-v)%N].
//
// ws (bf16): W1t[144][256]@0      : cas(2pi (64+c) m /256)
//            W2 [128][512]@36864  : k<256 cos(2pi(64+u)k/256), k>=256 sin
//            W3t[128][128]@102400 : cas(2pi c m /128)
//            W4 [128][256]@118784 : k<128 cos(2pi u k/128), k>=128 sin
//
// LDS timeline (bf16 elems, one 34,816-elem region = 69,632 B):
//   Phase A/B : PT   [129 rows x stride 264] @0      (P^T, bf16)
//   post-B    : Dcb  [128 x stride 136]      @0      (Dc, bf16)
//   A2 out    : P2T  [128 x stride 136]      @17408
//   B2 out    : outS [64 x stride 132] fp32  @byte 0 (overlays dead Dcb), 2 passes
// Strides 264/136 el = 4-bank row shift -> b128 fragment reads are 2-way (free).
// ---------------------------------------------------------------------------

typedef __attribute__((ext_vector_type(8))) short bfrag;
typedef __attribute__((ext_vector_type(4))) float ffrag;

#define PI2_256 0.0245436926061702597f
#define PI2_128 0.0490873852123405194f

constexpr int PT_S   = 264;
constexpr int DCB_E  = 0;
constexpr int P2T_E  = 17408;
constexpr int SM_EL  = 34816;   // 69,632 B

__device__ __forceinline__ unsigned short f2bf(float f) {
    union { float f; unsigned int u; } v; v.f = f;
    unsigned int r = v.u + 0x7fffu + ((v.u >> 16) & 1u);
    return (unsigned short)(r >> 16);
}

__device__ __forceinline__ bfrag pack8(float4 a, float4 b) {
    bfrag r;
    r[0] = (short)f2bf(a.x); r[1] = (short)f2bf(a.y);
    r[2] = (short)f2bf(a.z); r[3] = (short)f2bf(a.w);
    r[4] = (short)f2bf(b.x); r[5] = (short)f2bf(b.y);
    r[6] = (short)f2bf(b.z); r[7] = (short)f2bf(b.w);
    return r;
}

__device__ __forceinline__ uint2 packacc(ffrag a) {
    uint2 r;
    r.x = (unsigned)f2bf(a[0]) | ((unsigned)f2bf(a[1]) << 16);
    r.y = (unsigned)f2bf(a[2]) | ((unsigned)f2bf(a[3]) << 16);
    return r;
}

// ---------------------------------------------------------------------------
__global__ __launch_bounds__(256) void gen_tables(unsigned short* __restrict__ ws)
{
    const int id = blockIdx.x * 256 + threadIdx.x;   // 65536 threads
    {
        const int u = id >> 9, k = id & 511;
        const int up = 64 + u;
        float s, c, val;
        if (k < 256) { sincosf((float)((up * k) & 255) * PI2_256, &s, &c); val = c; }
        else         { sincosf((float)((up * (k - 256)) & 255) * PI2_256, &s, &c); val = s; }
        ws[36864 + id] = f2bf(val);
    }
    if (id < 36864) {   // W1t
        const int c = id >> 8, m = id & 255;
        float s, cc; sincosf((float)(((64 + c) * m) & 255) * PI2_256, &s, &cc);
        ws[id] = f2bf(cc + s);
    }
    if (id < 16384) {   // W3t
        const int c = id >> 7, m = id & 127;
        float s, cc; sincosf((float)((c * m) & 127) * PI2_128, &s, &cc);
        ws[102400 + id] = f2bf(cc + s);
    }
    if (id < 32768) {   // W4
        const int u = id >> 8, k = id & 255;
        float s, c, val;
        if (k < 128) { sincosf((float)((u * k) & 127) * PI2_128, &s, &c); val = c; }
        else         { sincosf((float)((u * (k - 128)) & 127) * PI2_128, &s, &c); val = s; }
        ws[118784 + id] = f2bf(val);
    }
}

// ---------------------------------------------------------------------------
__global__ __launch_bounds__(512, 4) void fused(const float* __restrict__ X,
                                                const unsigned short* __restrict__ ws,
                                                float* __restrict__ out)
{
    __shared__ unsigned short sm[SM_EL];
    float* outS = (float*)sm;   // 64 x stride 132 fp32 (33,792 B, within Dcb region)

    const int t  = threadIdx.x;
    const int w  = t >> 6;          // wave 0..7
    const int ln = t & 15;
    const int q  = (t & 63) >> 4;

    const float* __restrict__ Xi = X + (size_t)blockIdx.x * 65536;
    const unsigned short* __restrict__ W1 = ws;
    const unsigned short* __restrict__ W2 = ws + 36864;
    const unsigned short* __restrict__ W3 = ws + 102400;
    const unsigned short* __restrict__ W4 = ws + 118784;

    // ---- Phase A: PT[c][n] = sum_m X[n][m] W1t[c][m], c in [0,128] ----
    // Wave w owns n in [32w, 32w+32), two 16-row passes; A-frags from global X.
#pragma unroll
    for (int half = 0; half < 2; ++half) {
        const int n0 = w * 32 + half * 16;
        ffrag acc[9];
#pragma unroll
        for (int i = 0; i < 9; ++i) acc[i] = (ffrag){0.f, 0.f, 0.f, 0.f};

        const float* __restrict__ xrow = Xi + (size_t)(n0 + ln) * 256;
#pragma unroll
        for (int kk = 0; kk < 8; ++kk) {
            const int k = kk * 32 + q * 8;
            const bfrag A = pack8(*(const float4*)(xrow + k),
                                  *(const float4*)(xrow + k + 4));
#pragma unroll
            for (int ct = 0; ct < 9; ++ct) {
                const bfrag B = *(const bfrag*)(W1 + (ct * 16 + ln) * 256 + k);
                acc[ct] = __builtin_amdgcn_mfma_f32_16x16x32_bf16(A, B, acc[ct], 0, 0, 0);
            }
        }
        const int nb = n0 + 4 * q;
#pragma unroll
        for (int ct = 0; ct < 9; ++ct) {
            const int cc = ct * 16 + ln;
            if (cc <= 128)
                *(uint2*)&sm[cc * PT_S + nb] = packacc(acc[ct]);
        }
    }
    __syncthreads();

    // ---- Phase B: Dc[u][v] = sum_{k<256} W2[u][k] PT[v][k]
    //                        + sum_{k>=256} W2[u][k] PT[128-v][k-256] ----
    {
        const int u0 = w * 16;
        ffrag acc[8];
#pragma unroll
        for (int i = 0; i < 8; ++i) acc[i] = (ffrag){0.f, 0.f, 0.f, 0.f};

#pragma unroll
        for (int kk = 0; kk < 16; ++kk) {
            const int k = kk * 32 + q * 8;
            const bfrag A = *(const bfrag*)(W2 + (size_t)(u0 + ln) * 512 + k);
            const bool lo = (kk < 8);
#pragma unroll
            for (int nt = 0; nt < 8; ++nt) {
                const int v   = nt * 16 + ln;
                const int row = lo ? v : (128 - v);
                const int col = lo ? k : (k - 256);
                const bfrag B = *(const bfrag*)&sm[row * PT_S + col];
                acc[nt] = __builtin_amdgcn_mfma_f32_16x16x32_bf16(A, B, acc[nt], 0, 0, 0);
            }
        }
        __syncthreads();   // all PT reads done before Dcb overlays it
#pragma unroll
        for (int nt = 0; nt < 8; ++nt) {
            const int v = nt * 16 + ln;
#pragma unroll
            for (int r = 0; r < 4; ++r)
                sm[DCB_E + (u0 + 4 * q + r) * 136 + v] = f2bf(acc[nt][r]);
        }
    }
    __syncthreads();

    // ---- Phase A2: P2T[c][p] = sum_m Dcb[p][m] W3t[c][m] ----
    {
        const int p0 = w * 16;
        ffrag acc[8];
#pragma unroll
        for (int i = 0; i < 8; ++i) acc[i] = (ffrag){0.f, 0.f, 0.f, 0.f};

#pragma unroll
        for (int kk = 0; kk < 4; ++kk) {
            const int k = kk * 32 + q * 8;
            const bfrag A = *(const bfrag*)&sm[DCB_E + (p0 + ln) * 136 + k];
#pragma unroll
            for (int ct = 0; ct < 8; ++ct) {
                const bfrag B = *(const bfrag*)(W3 + (ct * 16 + ln) * 128 + k);
                acc[ct] = __builtin_amdgcn_mfma_f32_16x16x32_bf16(A, B, acc[ct], 0, 0, 0);
            }
        }
#pragma unroll
        for (int ct = 0; ct < 8; ++ct) {
            const int cc = ct * 16 + ln;
            *(uint2*)&sm[P2T_E + cc * 136 + p0 + 4 * q] = packacc(acc[ct]);
        }
    }
    __syncthreads();   // P2T complete; Dcb reads complete (outS overlay safe)

    // ---- Phase B2 + staged output ----
    {
        const int u0 = w * 16;
        ffrag o[8];
#pragma unroll
        for (int i = 0; i < 8; ++i) o[i] = (ffrag){0.f, 0.f, 0.f, 0.f};

#pragma unroll
        for (int kk = 0; kk < 8; ++kk) {
            const int k = kk * 32 + q * 8;
            const bfrag A = *(const bfrag*)(W4 + (size_t)(u0 + ln) * 256 + k);
            const bool lo = (kk < 4);
#pragma unroll
            for (int nt = 0; nt < 8; ++nt) {
                const int v   = nt * 16 + ln;
                const int row = lo ? v : ((128 - v) & 127);
                const int col = lo ? k : (k - 128);
                const bfrag B = *(const bfrag*)&sm[P2T_E + row * 136 + col];
                o[nt] = __builtin_amdgcn_mfma_f32_16x16x32_bf16(A, B, o[nt], 0, 0, 0);
            }
        }

        float* __restrict__ G = out + (size_t)blockIdx.x * 16384;
#pragma unroll
        for (int pass = 0; pass < 2; ++pass) {
            if ((w >> 2) == pass) {        // waves owning u in [64*pass, 64*pass+64)
                const int ul0 = (w & 3) * 16;
#pragma unroll
                for (int nt = 0; nt < 8; ++nt) {
                    const int v = nt * 16 + ln;
#pragma unroll
                    for (int r = 0; r < 4; ++r)
                        outS[(ul0 + 4 * q + r) * 132 + v] = o[nt][r];
                }
            }
            __syncthreads();
            // coalesced full-line copy of 64 rows
#pragma unroll
            for (int i = 0; i < 4; ++i) {
                const int f = i * 512 + t;
                const int u = f >> 5, v4 = f & 31;
                *(float4*)&G[(pass * 64 + u) * 128 + v4 * 4] =
                    *(const float4*)&outS[u * 132 + v4 * 4];
            }
            __syncthreads();
        }
    }
}

// ---------------------------------------------------------------------------
extern "C" void kernel_launch(void* const* d_in, const int* in_sizes, int n_in,
                              void* d_out, int out_size, void* d_ws, size_t ws_size,
                              hipStream_t stream)
{
    const float* x = (const float*)d_in[0];
    float* out = (float*)d_out;
    unsigned short* tw = (unsigned short*)d_ws;   // needs 303,104 bytes

    gen_tables<<<dim3(256), dim3(256), 0, stream>>>(tw);
    fused<<<dim3(512), dim3(512), 0, stream>>>(x, tw, out);
}